// Round 5
// baseline (3190.462 us; speedup 1.0000x reference)
//
#include <hip/hip_runtime.h>
#include <hip/hip_bf16.h>

#define DEV static __device__ __forceinline__

typedef unsigned short u16;
typedef unsigned long long u64;
typedef __attribute__((ext_vector_type(8))) short short8;   // 8 bf16 (4 VGPRs) MFMA frag
typedef __attribute__((ext_vector_type(4))) float f32x4;    // MFMA accumulator

constexpr int V = 32000, H = 1024, B = 32, T = 256;
constexpr int BT = B * T;       // 8192 rows
constexpr int G  = 4 * H;       // 4096 gates
constexpr int NCH = V / 128;    // 250 col-chunks for softmax partials
constexpr int NWG2 = 256;       // persistent LSTM blocks (128 L0 + 128 L1), 1/CU
constexpr int RSTRIDE = 32 * 2048 + 2048;  // u16 per h-buffer (132KB incl 4KB pad)

// ---------------- workspace layout (bytes) ----------------
constexpr size_t SZ_WT    = (size_t)G * 2048 * 2;            // [4096][2048] bf16
constexpr size_t OFF_W0T  = 0;
constexpr size_t OFF_W1T  = OFF_W0T + SZ_WT;
constexpr size_t OFF_EBF  = OFF_W1T + SZ_WT;                 // [32000][1024] bf16
constexpr size_t OFF_XBF  = OFF_EBF + (size_t)V * H * 2;     // [8192][1024] bf16 (row = t*32+b)
constexpr size_t OFF_XP0  = OFF_XBF + (size_t)BT * H * 2;    // bf16 perm [t][wgu][b][q*8+uu]
constexpr size_t OFF_H1   = OFF_XP0 + (size_t)BT * G * 2;    // [8192][1024] bf16 (row = b*256+t)
constexpr size_t OFF_HSEQ = OFF_H1 + (size_t)BT * H * 2;     // R[0..T+1], write-once per tick
constexpr size_t SZ_HSEQ  = (size_t)(T + 2) * RSTRIDE * 2;
constexpr size_t OFF_SYNC = OFF_HSEQ + SZ_HSEQ;              // chain counters (8KB)
constexpr size_t OFF_PMAX = OFF_SYNC + 8192;                 // [8192][250] f32
constexpr size_t OFF_PSUM = OFF_PMAX + (size_t)BT * NCH * 4;
constexpr size_t OFF_LOSS = OFF_PSUM + (size_t)BT * NCH * 4; // [8192] f32

DEV u16 f2bf(float x) {  // RNE f32 -> bf16 bits
  union { float f; unsigned int u; } v; v.f = x;
  unsigned int r = v.u + 0x7fffu + ((v.u >> 16) & 1u);
  return (u16)(r >> 16);
}
DEV float bf2f(u16 b) {
  union { unsigned int u; float f; } v; v.u = ((unsigned int)b) << 16;
  return v.f;
}
DEV float sigm(float x) { return 1.f / (1.f + expf(-x)); }

DEV void gload_lds16(const u16* g, u16* l) {
  __builtin_amdgcn_global_load_lds(
      (__attribute__((address_space(1))) void*)g,
      (__attribute__((address_space(3))) void*)l, 16, 0, 0);
}

// ---------------- prep kernels ----------------

__global__ void k_transpose_cvt(const float* __restrict__ in, u16* __restrict__ out,
                                int R, int C) {
  __shared__ float tile[32][33];
  int bc = blockIdx.x * 32, br = blockIdx.y * 32;
  int tx = threadIdx.x & 31, ty0 = threadIdx.x >> 5;
#pragma unroll
  for (int i = 0; i < 4; ++i) {
    int ty = ty0 + i * 8;
    tile[ty][tx] = in[(size_t)(br + ty) * C + bc + tx];
  }
  __syncthreads();
#pragma unroll
  for (int i = 0; i < 4; ++i) {
    int ty = ty0 + i * 8;
    out[(size_t)(bc + ty) * R + br + tx] = f2bf(tile[tx][ty]);
  }
}

__global__ void k_cvt_bf16(const float* __restrict__ in, u16* __restrict__ out, int n4) {
  int i = blockIdx.x * blockDim.x + threadIdx.x;
  int stride = gridDim.x * blockDim.x;
  for (; i < n4; i += stride) {
    float4 v = ((const float4*)in)[i];
    ushort4 o;
    o.x = f2bf(v.x); o.y = f2bf(v.y); o.z = f2bf(v.z); o.w = f2bf(v.w);
    ((ushort4*)out)[i] = o;
  }
}

__global__ void k_gather_x(const float* __restrict__ emb, const int* __restrict__ inp,
                           u16* __restrict__ Xbf) {
  int row = blockIdx.x;
  int t = row >> 5, b = row & 31;
  int tok = inp[b * T + t];
  const float4* src = (const float4*)(emb + (size_t)tok * H);
  ushort4* dst = (ushort4*)(Xbf + (size_t)row * H);
  float4 v = src[threadIdx.x];
  ushort4 o;
  o.x = f2bf(v.x); o.y = f2bf(v.y); o.z = f2bf(v.z); o.w = f2bf(v.w);
  dst[threadIdx.x] = o;
}

__global__ void k_zero(unsigned int* __restrict__ p, int nwords) {
  int i = blockIdx.x * blockDim.x + threadIdx.x;
  int stride = gridDim.x * blockDim.x;
  for (; i < nwords; i += stride) p[i] = 0u;
}

// ---------------- 128x128 bf16 MFMA GEMM (m97 structure + T1 XCD swizzle) --
// CMODE 0: C f32 [M][ldc].  CMODE 1: C bf16, permuted [t][wgu][b][q*8+uu].
// Grid MUST satisfy (gridDim.x*gridDim.y) % 8 == 0 (bijective XCD swizzle).
template <bool SM_EPI, int CMODE>
__global__ __launch_bounds__(256)
void k_gemm(const u16* __restrict__ A, int lda,
            const u16* __restrict__ Bt, int ldb,
            float* __restrict__ C, int ldc,
            const float* __restrict__ bias, int K,
            float* __restrict__ pmax, float* __restrict__ psum, int nch) {
  __shared__ alignas(16) u16 ldsA[128 * 32];
  __shared__ alignas(16) u16 ldsB[128 * 32];
  __shared__ float2 red[128][2];

  // XCD-aware swizzle: consecutive blocks on one XCD share the A row-panel
  unsigned nwg = gridDim.x * gridDim.y;
  unsigned flat = blockIdx.y * gridDim.x + blockIdx.x;
  unsigned nf = (flat & 7) * (nwg >> 3) + (flat >> 3);
  unsigned bx = nf % gridDim.x, by = nf / gridDim.x;

  int tid = threadIdx.x, lane = tid & 63, w = tid >> 6;
  int row0 = by * 128, col0 = bx * 128;
  int wr = w >> 1, wc = w & 1;
  int c15 = lane & 15, q4 = lane >> 4;

  const u16* ag[2]; const u16* bg[2];
#pragma unroll
  for (int j = 0; j < 2; ++j) {
    int r = (j * 4 + w) * 16 + (lane >> 2);
    int k = (lane & 3) * 8;
    ag[j] = A + (size_t)(row0 + r) * lda + k;
    bg[j] = Bt + (size_t)(col0 + r) * ldb + k;
  }
  u16* lA0 = ldsA + (size_t)(0 + w) * 512;
  u16* lA1 = ldsA + (size_t)(4 + w) * 512;
  u16* lB0 = ldsB + (size_t)(0 + w) * 512;
  u16* lB1 = ldsB + (size_t)(4 + w) * 512;

  f32x4 acc[4][4];
#pragma unroll
  for (int m = 0; m < 4; ++m)
#pragma unroll
    for (int n = 0; n < 4; ++n) acc[m][n] = (f32x4){0.f, 0.f, 0.f, 0.f};

  int nk = K >> 5;
  for (int kk = 0; kk < nk; ++kk) {
    int kb = kk * 32;
    gload_lds16(ag[0] + kb, lA0);
    gload_lds16(ag[1] + kb, lA1);
    gload_lds16(bg[0] + kb, lB0);
    gload_lds16(bg[1] + kb, lB1);
    __syncthreads();

    short8 af[4], bfr[4];
#pragma unroll
    for (int m = 0; m < 4; ++m)
      af[m] = *(const short8*)(ldsA + (wr * 64 + m * 16 + c15) * 32 + q4 * 8);
#pragma unroll
    for (int n = 0; n < 4; ++n)
      bfr[n] = *(const short8*)(ldsB + (wc * 64 + n * 16 + c15) * 32 + q4 * 8);
#pragma unroll
    for (int m = 0; m < 4; ++m)
#pragma unroll
      for (int n = 0; n < 4; ++n)
        acc[m][n] = __builtin_amdgcn_mfma_f32_16x16x32_bf16(af[m], bfr[n], acc[m][n], 0, 0, 0);
    __syncthreads();
  }

  float bias_n[4];
#pragma unroll
  for (int n = 0; n < 4; ++n) bias_n[n] = bias[col0 + wc * 64 + n * 16 + c15];

#pragma unroll
  for (int m = 0; m < 4; ++m) {
#pragma unroll
    for (int jr = 0; jr < 4; ++jr) {
      int r_g = row0 + wr * 64 + m * 16 + q4 * 4 + jr;
      float v[4];
#pragma unroll
      for (int n = 0; n < 4; ++n) {
        int c_g = col0 + wc * 64 + n * 16 + c15;
        float val = acc[m][n][jr] + bias_n[n];
        if (CMODE == 0) {
          C[(size_t)r_g * ldc + c_g] = val;
        } else {
          int tt = r_g >> 5, bb = r_g & 31;
          int q = c_g >> 10, wgup = (c_g & 1023) >> 3, uu = c_g & 7;
          ((u16*)C)[((((size_t)tt * 128 + wgup) * 32 + bb) * 32) + q * 8 + uu] = f2bf(val);
        }
        v[n] = val;
      }
      if (SM_EPI) {
        float mx = fmaxf(fmaxf(v[0], v[1]), fmaxf(v[2], v[3]));
        float s = __expf(v[0] - mx) + __expf(v[1] - mx) + __expf(v[2] - mx) + __expf(v[3] - mx);
#pragma unroll
        for (int d = 1; d < 16; d <<= 1) {
          float mo = __shfl_xor(mx, d, 64);
          float so = __shfl_xor(s, d, 64);
          float M2 = fmaxf(mx, mo);
          s = s * __expf(mx - M2) + so * __expf(mo - M2);
          mx = M2;
        }
        if (c15 == 0) red[wr * 64 + m * 16 + q4 * 4 + jr][wc] = make_float2(mx, s);
      }
    }
  }
  if (SM_EPI) {
    __syncthreads();
    if (tid < 128) {
      float2 a = red[tid][0], b2 = red[tid][1];
      float M2 = fmaxf(a.x, b2.x);
      float S = a.y * __expf(a.x - M2) + b2.y * __expf(b2.x - M2);
      pmax[(size_t)(row0 + tid) * nch + bx] = M2;
      psum[(size_t)(row0 + tid) * nch + bx] = S;
    }
  }
}

// ---------------- persistent LSTM: weights in registers, decoupled chains --
// Blocks 0..127 = layer0 (8 units each): private 128-barrier, runs AHEAD
// (never reads L1 output; hseq is write-once per tick -> no WAR hazard).
// Blocks 128..255 = layer1: waits on L0's epoch counter + its own 128-barrier.
// Barrier = single counter polled directly (one dependent L3 hop each way).

#define RED(w_, bt_, nt_, r_, c_) red[((((w_)*2 + (bt_)) * 2 + (nt_)) * 16 + (r_)) * 16 + (c_)]

DEV void bar_sync(int* __restrict__ cnt, int target) {
  __syncthreads();   // drains each wave's vmcnt: h-stores acked at coherence pt
  if (threadIdx.x == 0) {
    __hip_atomic_fetch_add(cnt, 1, __ATOMIC_RELAXED, __HIP_MEMORY_SCOPE_AGENT);
    while (__hip_atomic_load(cnt, __ATOMIC_RELAXED, __HIP_MEMORY_SCOPE_AGENT) < target)
      __builtin_amdgcn_s_sleep(4);
  }
  __builtin_amdgcn_sched_barrier(0);
  __syncthreads();
}

DEV void epoch_wait(const int* __restrict__ cnt, int target) {
  if (threadIdx.x == 0) {
    while (__hip_atomic_load(cnt, __ATOMIC_RELAXED, __HIP_MEMORY_SCOPE_AGENT) < target)
      __builtin_amdgcn_s_sleep(4);
  }
  __builtin_amdgcn_sched_barrier(0);
  __syncthreads();
}

template <int KH, bool IS_L0>
DEV void lstm_role(const u16* __restrict__ WT,      // [4096][2048] bf16
                   const u16* __restrict__ xp0p,    // bf16 perm (L0) or null
                   const float* __restrict__ zb1,   // b1 (L1) or null
                   u16* __restrict__ hseq, u16* __restrict__ H1bf,
                   int* __restrict__ c_own, int* __restrict__ c_epoch,
                   float* __restrict__ red, int wgu) {
  constexpr int KOFF = IS_L0 ? 1024 : 0;   // weight-k offset (h-part of W0)
  constexpr int KS = KH / 4;               // per-wave K slice
  constexpr int NKC = KS / 32;             // k-chunks per wave (8 or 16)
  int tid = threadIdx.x, lane = tid & 63, w = tid >> 6;
  int c15 = lane & 15, q4 = lane >> 4;
  int eb = tid >> 3, eu = tid & 7;         // epilogue identity: (b, unit)

  // ---- preload weight slice into registers (once) ----
  short8 wfr[2][NKC];
#pragma unroll
  for (int nt = 0; nt < 2; ++nt) {
    int lr = nt * 16 + c15;                // local row = gate*8 + unit
    const u16* rp = WT + (size_t)((lr >> 3) * 1024 + wgu * 8 + (lr & 7)) * 2048
                    + KOFF + w * KS + q4 * 8;
#pragma unroll
    for (int kc = 0; kc < NKC; ++kc)
      wfr[nt][kc] = *(const short8*)(rp + kc * 32);
  }

  float zpc[4];
  if (!IS_L0) {
#pragma unroll
    for (int q = 0; q < 4; ++q) zpc[q] = zb1[q * 1024 + wgu * 8 + eu];
  }
  float creg = 0.f;                        // c-state lives in a register

  for (int it_t = 0; it_t < T; ++it_t) {
    int t = IS_L0 ? it_t : it_t + 1;       // L0 computes h0(t); L1 computes h1(t-1)

    if (!IS_L0) epoch_wait(c_epoch, 128 * t);   // h0(t-1) in R[t] ready

    float zp[4];
    if (IS_L0) {
#pragma unroll
      for (int q = 0; q < 4; ++q)
        zp[q] = bf2f(xp0p[((((size_t)t * 128 + wgu) * 32 + eb) * 32) + q * 8 + eu]);
    } else {
#pragma unroll
      for (int q = 0; q < 4; ++q) zp[q] = zpc[q];
    }

    const u16* hread = hseq + (size_t)t * RSTRIDE;
    f32x4 acc[2][2];
#pragma unroll
    for (int bt = 0; bt < 2; ++bt)
#pragma unroll
      for (int nt = 0; nt < 2; ++nt) acc[bt][nt] = (f32x4){0.f, 0.f, 0.f, 0.f};

#pragma unroll
    for (int kc = 0; kc < NKC; ++kc) {
      int kh = w * KS + kc * 32 + q4 * 8;
      short8 a0 = *(const short8*)(hread + (size_t)c15 * 2048 + kh);
      short8 a1 = *(const short8*)(hread + (size_t)(16 + c15) * 2048 + kh);
      acc[0][0] = __builtin_amdgcn_mfma_f32_16x16x32_bf16(a0, wfr[0][kc], acc[0][0], 0, 0, 0);
      acc[0][1] = __builtin_amdgcn_mfma_f32_16x16x32_bf16(a0, wfr[1][kc], acc[0][1], 0, 0, 0);
      acc[1][0] = __builtin_amdgcn_mfma_f32_16x16x32_bf16(a1, wfr[0][kc], acc[1][0], 0, 0, 0);
      acc[1][1] = __builtin_amdgcn_mfma_f32_16x16x32_bf16(a1, wfr[1][kc], acc[1][1], 0, 0, 0);
    }

    // cross-wave K reduction via LDS
#pragma unroll
    for (int bt = 0; bt < 2; ++bt)
#pragma unroll
      for (int nt = 0; nt < 2; ++nt)
#pragma unroll
        for (int jr = 0; jr < 4; ++jr)
          RED(w, bt, nt, q4 * 4 + jr, c15) = acc[bt][nt][jr];
    __syncthreads();

    // epilogue: thread = (b=eb, unit=eu)
    int bt = eb >> 4, rr = eb & 15;
    float z[4];
#pragma unroll
    for (int q = 0; q < 4; ++q) {
      int lr = q * 8 + eu, nt = lr >> 4, cc = lr & 15;
      z[q] = RED(0, bt, nt, rr, cc) + RED(1, bt, nt, rr, cc) +
             RED(2, bt, nt, rr, cc) + RED(3, bt, nt, rr, cc) + zp[q];
    }
    float gi = sigm(z[0]);
    float gj = tanhf(z[1]);
    float gf = sigm(z[2] + 1.f);   // forget_bias = 1.0
    float go = sigm(z[3]);
    creg = creg * gf + gi * gj;
    float hv = go * tanhf(creg);

    int hb = (int)f2bf(hv);
    int hp = __shfl_xor(hb, 1, 64);  // partner unit (eu^1), same b
    if (!(tid & 1)) {
      unsigned int pack = (unsigned int)(u16)hb | ((unsigned int)(u16)hp << 16);
      u16* hwr = hseq + (size_t)(t + 1) * RSTRIDE + (IS_L0 ? 0 : 1024);
      __hip_atomic_store((unsigned int*)(hwr + (size_t)eb * 2048 + wgu * 8 + eu), pack,
                         __ATOMIC_RELAXED, __HIP_MEMORY_SCOPE_AGENT);
      if (!IS_L0)
        *(unsigned int*)(H1bf + ((size_t)eb * T + (t - 1)) * H + wgu * 8 + eu) = pack;
    }

    bar_sync(c_own, 128 * (IS_L0 ? t + 1 : t));
  }
}

__global__ __launch_bounds__(256, 1)
void k_lstm_persistent(const u16* __restrict__ W0T, const u16* __restrict__ W1T,
                       const u16* __restrict__ xp0p, const float* __restrict__ b1,
                       u16* __restrict__ hseq, u16* __restrict__ H1bf,
                       int* __restrict__ sync) {
  __shared__ float red[4 * 2 * 2 * 16 * 16];   // 16KB
  int wg = blockIdx.x;
  if (wg < 128)
    lstm_role<1024, true>(W0T, xp0p, nullptr, hseq, H1bf, sync, nullptr, red, wg);
  else
    lstm_role<2048, false>(W1T, nullptr, b1, hseq, H1bf, sync + 64, sync, red, wg - 128);
}

// ---------------- softmax finalize ----------------
__global__ void k_rowfin(const float* __restrict__ pmax, const float* __restrict__ psum,
                         const float* __restrict__ Cl, const int* __restrict__ targets,
                         float* __restrict__ loss) {
  int row = blockIdx.x;
  int tid = threadIdx.x, lane = tid & 63, w = tid >> 6;
  float mx = -1e30f, s = 0.f;
  if (tid < NCH) { mx = pmax[(size_t)row * NCH + tid]; s = psum[(size_t)row * NCH + tid]; }
#pragma unroll
  for (int d = 1; d < 64; d <<= 1) {
    float mo = __shfl_xor(mx, d, 64);
    float so = __shfl_xor(s, d, 64);
    float M2 = fmaxf(mx, mo);
    s = s * __expf(mx - M2) + so * __expf(mo - M2);
    mx = M2;
  }
  __shared__ float2 wred[4];
  if (lane == 0) wred[w] = make_float2(mx, s);
  __syncthreads();
  if (tid == 0) {
    float M = wred[0].x, S = wred[0].y;
#pragma unroll
    for (int i = 1; i < 4; ++i) {
      float M2 = fmaxf(M, wred[i].x);
      S = S * __expf(M - M2) + wred[i].y * __expf(wred[i].x - M2);
      M = M2;
    }
    float logZ = M + logf(S);
    int tgt = targets[row];
    float xt = Cl[(size_t)row * V + tgt];
    loss[row] = logZ - xt;
  }
}

__global__ void k_cost(const float* __restrict__ loss, float* __restrict__ out) {
  int tid = threadIdx.x, lane = tid & 63, w = tid >> 6;
  float s = 0.f;
  for (int i = tid; i < BT; i += 256) s += loss[i];
#pragma unroll
  for (int d = 1; d < 64; d <<= 1) s += __shfl_xor(s, d, 64);
  __shared__ float ws4[4];
  if (lane == 0) ws4[w] = s;
  __syncthreads();
  if (tid == 0) out[0] = (ws4[0] + ws4[1] + ws4[2] + ws4[3]) * (1.0f / B);
}

// ---------------- host ----------------
extern "C" void kernel_launch(void* const* d_in, const int* in_sizes, int n_in,
                              void* d_out, int out_size, void* d_ws, size_t ws_size,
                              hipStream_t stream) {
  const int*   input_data = (const int*)d_in[0];
  const int*   targets    = (const int*)d_in[1];
  const float* emb        = (const float*)d_in[2];
  const float* softmax_b  = (const float*)d_in[3];
  const float* W0         = (const float*)d_in[4];
  const float* b0         = (const float*)d_in[5];
  const float* W1         = (const float*)d_in[6];
  const float* b1         = (const float*)d_in[7];
  float* out = (float*)d_out;
  char*  ws  = (char*)d_ws;

  u16*   W0T  = (u16*)(ws + OFF_W0T);
  u16*   W1T  = (u16*)(ws + OFF_W1T);
  u16*   Ebf  = (u16*)(ws + OFF_EBF);
  u16*   Xbf  = (u16*)(ws + OFF_XBF);
  u16*   xp0p = (u16*)(ws + OFF_XP0);
  u16*   H1bf = (u16*)(ws + OFF_H1);
  u16*   hseq = (u16*)(ws + OFF_HSEQ);
  int*   sync = (int*)(ws + OFF_SYNC);
  float* pmax = (float*)(ws + OFF_PMAX);
  float* psum = (float*)(ws + OFF_PSUM);
  float* lossb= (float*)(ws + OFF_LOSS);

  // prep: weight transposes (bf16), embedding convert, X gather, R[0..1]/sync zero
  k_transpose_cvt<<<dim3(G / 32, 2048 / 32), 256, 0, stream>>>(W0, W0T, 2048, G);
  k_transpose_cvt<<<dim3(G / 32, 2048 / 32), 256, 0, stream>>>(W1, W1T, 2048, G);
  k_cvt_bf16<<<2048, 256, 0, stream>>>(emb, Ebf, V * H / 4);
  k_gather_x<<<BT, 256, 0, stream>>>(emb, input_data, Xbf);
  k_zero<<<64, 256, 0, stream>>>((unsigned int*)(ws + OFF_HSEQ), RSTRIDE);  // R[0],R[1]
  k_zero<<<1, 256, 0, stream>>>((unsigned int*)(ws + OFF_SYNC), 2048);

  // xp0p = X @ W0[0:1024,:] + b0  (bf16, block-permuted layout)
  k_gemm<false, 1><<<dim3(G / 128, BT / 128), 256, 0, stream>>>(
      Xbf, H, W0T, 2048, (float*)xp0p, G, b0, H, nullptr, nullptr, 0);

  // persistent pipelined LSTM: decoupled L0/L1 chains, weights in VGPRs
  k_lstm_persistent<<<dim3(NWG2), dim3(256), 0, stream>>>(
      W0T, W1T, xp0p, b1, hseq, H1bf, sync);

  // logits = H1 @ E^T + softmax_b, fused online-softmax partials
  k_gemm<true, 0><<<dim3(V / 128, BT / 128), 256, 0, stream>>>(
      H1bf, H, Ebf, H, out, V, softmax_b, H, pmax, psum, NCH);

  // per-row logZ + NLL, then cost = sum/B appended after logits
  k_rowfin<<<BT, 256, 0, stream>>>(pmax, psum, out, targets, lossb);
  k_cost<<<1, 256, 0, stream>>>(lossb, out + (size_t)BT * V);
}

// Round 6
// 2997.019 us; speedup vs baseline: 1.0645x; 1.0645x over previous
//
#include <hip/hip_runtime.h>
#include <hip/hip_bf16.h>

#define DEV static __device__ __forceinline__

typedef unsigned short u16;
typedef unsigned long long u64;
typedef __attribute__((ext_vector_type(8))) short short8;   // 8 bf16 (4 VGPRs) MFMA frag
typedef __attribute__((ext_vector_type(4))) float f32x4;    // MFMA accumulator

constexpr int V = 32000, H = 1024, B = 32, T = 256;
constexpr int BT = B * T;       // 8192 rows
constexpr int G  = 4 * H;       // 4096 gates
constexpr int NCH = V / 128;    // 250 col-chunks for softmax partials
constexpr int NWG2 = 256;       // persistent LSTM blocks (128 L0 + 128 L1), 1/CU
constexpr int RSTRIDE = 32 * 2048 + 2048;  // u16 per h-buffer (132KB incl 4KB pad)

// ---------------- workspace layout (bytes) ----------------
constexpr size_t SZ_WT    = (size_t)G * 2048 * 2;            // [4096][2048] bf16
constexpr size_t OFF_W0T  = 0;
constexpr size_t OFF_W1T  = OFF_W0T + SZ_WT;
constexpr size_t OFF_EBF  = OFF_W1T + SZ_WT;                 // [32000][1024] bf16
constexpr size_t OFF_XBF  = OFF_EBF + (size_t)V * H * 2;     // [8192][1024] bf16 (row = t*32+b)
constexpr size_t OFF_XP0  = OFF_XBF + (size_t)BT * H * 2;    // bf16 perm [t][wgu][b][q*8+uu]
constexpr size_t OFF_H1   = OFF_XP0 + (size_t)BT * G * 2;    // [8192][1024] bf16 (row = b*256+t)
constexpr size_t OFF_HSEQ = OFF_H1 + (size_t)BT * H * 2;     // R[0..T+1], write-once per tick
constexpr size_t SZ_HSEQ  = (size_t)(T + 2) * RSTRIDE * 2;
constexpr size_t OFF_SYNC = OFF_HSEQ + SZ_HSEQ;              // flags f0/f1 [256][128] ints
constexpr size_t SZ_SYNC  = (size_t)2 * 256 * 128 * 4;       // 256KB
constexpr size_t OFF_PMAX = OFF_SYNC + SZ_SYNC;              // [8192][250] f32
constexpr size_t OFF_PSUM = OFF_PMAX + (size_t)BT * NCH * 4;
constexpr size_t OFF_LOSS = OFF_PSUM + (size_t)BT * NCH * 4; // [8192] f32

DEV u16 f2bf(float x) {  // RNE f32 -> bf16 bits
  union { float f; unsigned int u; } v; v.f = x;
  unsigned int r = v.u + 0x7fffu + ((v.u >> 16) & 1u);
  return (u16)(r >> 16);
}
DEV float bf2f(u16 b) {
  union { unsigned int u; float f; } v; v.u = ((unsigned int)b) << 16;
  return v.f;
}
DEV float sigm(float x) { return 1.f / (1.f + expf(-x)); }

DEV void gload_lds16(const u16* g, u16* l) {
  __builtin_amdgcn_global_load_lds(
      (__attribute__((address_space(1))) void*)g,
      (__attribute__((address_space(3))) void*)l, 16, 0, 0);
}

// ---------------- prep kernels ----------------

__global__ void k_transpose_cvt(const float* __restrict__ in, u16* __restrict__ out,
                                int R, int C) {
  __shared__ float tile[32][33];
  int bc = blockIdx.x * 32, br = blockIdx.y * 32;
  int tx = threadIdx.x & 31, ty0 = threadIdx.x >> 5;
#pragma unroll
  for (int i = 0; i < 4; ++i) {
    int ty = ty0 + i * 8;
    tile[ty][tx] = in[(size_t)(br + ty) * C + bc + tx];
  }
  __syncthreads();
#pragma unroll
  for (int i = 0; i < 4; ++i) {
    int ty = ty0 + i * 8;
    out[(size_t)(bc + ty) * R + br + tx] = f2bf(tile[tx][ty]);
  }
}

__global__ void k_cvt_bf16(const float* __restrict__ in, u16* __restrict__ out, int n4) {
  int i = blockIdx.x * blockDim.x + threadIdx.x;
  int stride = gridDim.x * blockDim.x;
  for (; i < n4; i += stride) {
    float4 v = ((const float4*)in)[i];
    ushort4 o;
    o.x = f2bf(v.x); o.y = f2bf(v.y); o.z = f2bf(v.z); o.w = f2bf(v.w);
    ((ushort4*)out)[i] = o;
  }
}

__global__ void k_gather_x(const float* __restrict__ emb, const int* __restrict__ inp,
                           u16* __restrict__ Xbf) {
  int row = blockIdx.x;
  int t = row >> 5, b = row & 31;
  int tok = inp[b * T + t];
  const float4* src = (const float4*)(emb + (size_t)tok * H);
  ushort4* dst = (ushort4*)(Xbf + (size_t)row * H);
  float4 v = src[threadIdx.x];
  ushort4 o;
  o.x = f2bf(v.x); o.y = f2bf(v.y); o.z = f2bf(v.z); o.w = f2bf(v.w);
  dst[threadIdx.x] = o;
}

__global__ void k_zero(unsigned int* __restrict__ p, int nwords) {
  int i = blockIdx.x * blockDim.x + threadIdx.x;
  int stride = gridDim.x * blockDim.x;
  for (; i < nwords; i += stride) p[i] = 0u;
}

// ---------------- 128x128 bf16 MFMA GEMM (m97 structure + T1 XCD swizzle) --
// CMODE 0: C f32 [M][ldc].  CMODE 1: C bf16, permuted [t][wgu][b][q*8+uu].
// Grid MUST satisfy (gridDim.x*gridDim.y) % 8 == 0 (bijective XCD swizzle).
template <bool SM_EPI, int CMODE>
__global__ __launch_bounds__(256)
void k_gemm(const u16* __restrict__ A, int lda,
            const u16* __restrict__ Bt, int ldb,
            float* __restrict__ C, int ldc,
            const float* __restrict__ bias, int K,
            float* __restrict__ pmax, float* __restrict__ psum, int nch) {
  __shared__ alignas(16) u16 ldsA[128 * 32];
  __shared__ alignas(16) u16 ldsB[128 * 32];
  __shared__ float2 red[128][2];

  // XCD-aware swizzle: consecutive blocks on one XCD share the A row-panel
  unsigned nwg = gridDim.x * gridDim.y;
  unsigned flat = blockIdx.y * gridDim.x + blockIdx.x;
  unsigned nf = (flat & 7) * (nwg >> 3) + (flat >> 3);
  unsigned bx = nf % gridDim.x, by = nf / gridDim.x;

  int tid = threadIdx.x, lane = tid & 63, w = tid >> 6;
  int row0 = by * 128, col0 = bx * 128;
  int wr = w >> 1, wc = w & 1;
  int c15 = lane & 15, q4 = lane >> 4;

  const u16* ag[2]; const u16* bg[2];
#pragma unroll
  for (int j = 0; j < 2; ++j) {
    int r = (j * 4 + w) * 16 + (lane >> 2);
    int k = (lane & 3) * 8;
    ag[j] = A + (size_t)(row0 + r) * lda + k;
    bg[j] = Bt + (size_t)(col0 + r) * ldb + k;
  }
  u16* lA0 = ldsA + (size_t)(0 + w) * 512;
  u16* lA1 = ldsA + (size_t)(4 + w) * 512;
  u16* lB0 = ldsB + (size_t)(0 + w) * 512;
  u16* lB1 = ldsB + (size_t)(4 + w) * 512;

  f32x4 acc[4][4];
#pragma unroll
  for (int m = 0; m < 4; ++m)
#pragma unroll
    for (int n = 0; n < 4; ++n) acc[m][n] = (f32x4){0.f, 0.f, 0.f, 0.f};

  int nk = K >> 5;
  for (int kk = 0; kk < nk; ++kk) {
    int kb = kk * 32;
    gload_lds16(ag[0] + kb, lA0);
    gload_lds16(ag[1] + kb, lA1);
    gload_lds16(bg[0] + kb, lB0);
    gload_lds16(bg[1] + kb, lB1);
    __syncthreads();

    short8 af[4], bfr[4];
#pragma unroll
    for (int m = 0; m < 4; ++m)
      af[m] = *(const short8*)(ldsA + (wr * 64 + m * 16 + c15) * 32 + q4 * 8);
#pragma unroll
    for (int n = 0; n < 4; ++n)
      bfr[n] = *(const short8*)(ldsB + (wc * 64 + n * 16 + c15) * 32 + q4 * 8);
#pragma unroll
    for (int m = 0; m < 4; ++m)
#pragma unroll
      for (int n = 0; n < 4; ++n)
        acc[m][n] = __builtin_amdgcn_mfma_f32_16x16x32_bf16(af[m], bfr[n], acc[m][n], 0, 0, 0);
    __syncthreads();
  }

  float bias_n[4];
#pragma unroll
  for (int n = 0; n < 4; ++n) bias_n[n] = bias[col0 + wc * 64 + n * 16 + c15];

#pragma unroll
  for (int m = 0; m < 4; ++m) {
#pragma unroll
    for (int jr = 0; jr < 4; ++jr) {
      int r_g = row0 + wr * 64 + m * 16 + q4 * 4 + jr;
      float v[4];
#pragma unroll
      for (int n = 0; n < 4; ++n) {
        int c_g = col0 + wc * 64 + n * 16 + c15;
        float val = acc[m][n][jr] + bias_n[n];
        if (CMODE == 0) {
          C[(size_t)r_g * ldc + c_g] = val;
        } else {
          int tt = r_g >> 5, bb = r_g & 31;
          int q = c_g >> 10, wgup = (c_g & 1023) >> 3, uu = c_g & 7;
          ((u16*)C)[((((size_t)tt * 128 + wgup) * 32 + bb) * 32) + q * 8 + uu] = f2bf(val);
        }
        v[n] = val;
      }
      if (SM_EPI) {
        float mx = fmaxf(fmaxf(v[0], v[1]), fmaxf(v[2], v[3]));
        float s = __expf(v[0] - mx) + __expf(v[1] - mx) + __expf(v[2] - mx) + __expf(v[3] - mx);
#pragma unroll
        for (int d = 1; d < 16; d <<= 1) {
          float mo = __shfl_xor(mx, d, 64);
          float so = __shfl_xor(s, d, 64);
          float M2 = fmaxf(mx, mo);
          s = s * __expf(mx - M2) + so * __expf(mo - M2);
          mx = M2;
        }
        if (c15 == 0) red[wr * 64 + m * 16 + q4 * 4 + jr][wc] = make_float2(mx, s);
      }
    }
  }
  if (SM_EPI) {
    __syncthreads();
    if (tid < 128) {
      float2 a = red[tid][0], b2 = red[tid][1];
      float M2 = fmaxf(a.x, b2.x);
      float S = a.y * __expf(a.x - M2) + b2.y * __expf(b2.x - M2);
      pmax[(size_t)(row0 + tid) * nch + bx] = M2;
      psum[(size_t)(row0 + tid) * nch + bx] = S;
    }
  }
}

// ---------------- persistent LSTM: weights in VGPRs, flag-sync chains -----
// Blocks 0..127 = layer0 (8 units each), 128..255 = layer1.
// Sync = write-once per-tick flag words (one per producer block): producer
// does __syncthreads (vmcnt drain -> h stores visible) then one relaxed
// agent store; consumers' wave 0 polls all 128 flags directly. No RMW, no
// line contention, ~1 L3 round-trip of latency. L0 runs ahead (hseq is
// write-once => no WAR hazard); L1 waits on f0[t-1] (usually pre-satisfied)
// and f1[t-2] (its own previous tick).

#define RED(w_, bt_, nt_, r_, c_) red[((((w_)*2 + (bt_)) * 2 + (nt_)) * 16 + (r_)) * 16 + (c_)]

DEV void wait_flags(const int* __restrict__ fa, const int* __restrict__ fb) {
  if (threadIdx.x < 64) {
    int lane = threadIdx.x;
    while (true) {
      int ok = 1;
      if (fa) {
        int a0 = __hip_atomic_load(fa + lane,      __ATOMIC_RELAXED, __HIP_MEMORY_SCOPE_AGENT);
        int a1 = __hip_atomic_load(fa + 64 + lane, __ATOMIC_RELAXED, __HIP_MEMORY_SCOPE_AGENT);
        ok &= (a0 != 0) & (a1 != 0);
      }
      if (fb) {
        int b0 = __hip_atomic_load(fb + lane,      __ATOMIC_RELAXED, __HIP_MEMORY_SCOPE_AGENT);
        int b1 = __hip_atomic_load(fb + 64 + lane, __ATOMIC_RELAXED, __HIP_MEMORY_SCOPE_AGENT);
        ok &= (b0 != 0) & (b1 != 0);
      }
      if (__all(ok)) break;
      __builtin_amdgcn_s_sleep(2);
    }
  }
  __builtin_amdgcn_sched_barrier(0);
  __syncthreads();
}

DEV void publish_flag(int* __restrict__ word) {
  __syncthreads();   // each wave's vmcnt drained -> agent h-stores at L3
  if (threadIdx.x == 0)
    __hip_atomic_store(word, 1, __ATOMIC_RELAXED, __HIP_MEMORY_SCOPE_AGENT);
}

template <int KH, bool IS_L0>
DEV void lstm_role(const u16* __restrict__ WT,      // [4096][2048] bf16
                   const u16* __restrict__ xp0p,    // bf16 perm (L0) or null
                   const float* __restrict__ zb1,   // b1 (L1) or null
                   u16* __restrict__ hseq, u16* __restrict__ H1bf,
                   int* __restrict__ f0, int* __restrict__ f1,
                   float* __restrict__ red, int wgu) {
  constexpr int KOFF = IS_L0 ? 1024 : 0;   // weight-k offset (h-part of W0)
  constexpr int KS = KH / 4;               // per-wave K slice
  constexpr int NKC = KS / 32;             // k-chunks per wave (8 or 16)
  int tid = threadIdx.x, lane = tid & 63, w = tid >> 6;
  int c15 = lane & 15, q4 = lane >> 4;
  int eb = tid >> 3, eu = tid & 7;         // epilogue identity: (b, unit)

  // ---- preload weight slice into registers (once) ----
  short8 wfr[2][NKC];
#pragma unroll
  for (int nt = 0; nt < 2; ++nt) {
    int lr = nt * 16 + c15;                // local row = gate*8 + unit
    const u16* rp = WT + (size_t)((lr >> 3) * 1024 + wgu * 8 + (lr & 7)) * 2048
                    + KOFF + w * KS + q4 * 8;
#pragma unroll
    for (int kc = 0; kc < NKC; ++kc)
      wfr[nt][kc] = *(const short8*)(rp + kc * 32);
  }

  float zpc[4];
  if (!IS_L0) {
#pragma unroll
    for (int q = 0; q < 4; ++q) zpc[q] = zb1[q * 1024 + wgu * 8 + eu];
  }
  float creg = 0.f;                        // c-state lives in a register

  for (int it_t = 0; it_t < T; ++it_t) {
    int t = IS_L0 ? it_t : it_t + 1;       // L0 computes h0(t); L1 computes h1(t-1)

    float zp[4];
    if (IS_L0) {
      // tick-private data: issue BEFORE the flag wait to hide latency
#pragma unroll
      for (int q = 0; q < 4; ++q)
        zp[q] = bf2f(xp0p[((((size_t)t * 128 + wgu) * 32 + eb) * 32) + q * 8 + eu]);
    } else {
#pragma unroll
      for (int q = 0; q < 4; ++q) zp[q] = zpc[q];
    }

    if (IS_L0) {
      if (t >= 1) wait_flags(f0 + (size_t)(t - 1) * 128, nullptr);  // h0(t-1)
    } else {
      wait_flags(f0 + (size_t)(t - 1) * 128,                        // h0(t-1)
                 t >= 2 ? f1 + (size_t)(t - 2) * 128 : nullptr);    // h1(t-2)
    }

    const u16* hread = hseq + (size_t)t * RSTRIDE;
    f32x4 acc[2][2];
#pragma unroll
    for (int bt = 0; bt < 2; ++bt)
#pragma unroll
      for (int nt = 0; nt < 2; ++nt) acc[bt][nt] = (f32x4){0.f, 0.f, 0.f, 0.f};

#pragma unroll
    for (int kc = 0; kc < NKC; ++kc) {
      int kh = w * KS + kc * 32 + q4 * 8;
      short8 a0 = *(const short8*)(hread + (size_t)c15 * 2048 + kh);
      short8 a1 = *(const short8*)(hread + (size_t)(16 + c15) * 2048 + kh);
      acc[0][0] = __builtin_amdgcn_mfma_f32_16x16x32_bf16(a0, wfr[0][kc], acc[0][0], 0, 0, 0);
      acc[0][1] = __builtin_amdgcn_mfma_f32_16x16x32_bf16(a0, wfr[1][kc], acc[0][1], 0, 0, 0);
      acc[1][0] = __builtin_amdgcn_mfma_f32_16x16x32_bf16(a1, wfr[0][kc], acc[1][0], 0, 0, 0);
      acc[1][1] = __builtin_amdgcn_mfma_f32_16x16x32_bf16(a1, wfr[1][kc], acc[1][1], 0, 0, 0);
    }

    // cross-wave K reduction via LDS
#pragma unroll
    for (int bt = 0; bt < 2; ++bt)
#pragma unroll
      for (int nt = 0; nt < 2; ++nt)
#pragma unroll
        for (int jr = 0; jr < 4; ++jr)
          RED(w, bt, nt, q4 * 4 + jr, c15) = acc[bt][nt][jr];
    __syncthreads();

    // epilogue: thread = (b=eb, unit=eu)
    int bt = eb >> 4, rr = eb & 15;
    float z[4];
#pragma unroll
    for (int q = 0; q < 4; ++q) {
      int lr = q * 8 + eu, nt = lr >> 4, cc = lr & 15;
      z[q] = RED(0, bt, nt, rr, cc) + RED(1, bt, nt, rr, cc) +
             RED(2, bt, nt, rr, cc) + RED(3, bt, nt, rr, cc) + zp[q];
    }
    float gi = sigm(z[0]);
    float gj = tanhf(z[1]);
    float gf = sigm(z[2] + 1.f);   // forget_bias = 1.0
    float go = sigm(z[3]);
    creg = creg * gf + gi * gj;
    float hv = go * tanhf(creg);

    int hb = (int)f2bf(hv);
    int hp = __shfl_xor(hb, 1, 64);  // partner unit (eu^1), same b
    if (!(tid & 1)) {
      unsigned int pack = (unsigned int)(u16)hb | ((unsigned int)(u16)hp << 16);
      u16* hwr = hseq + (size_t)(t + 1) * RSTRIDE + (IS_L0 ? 0 : 1024);
      __hip_atomic_store((unsigned int*)(hwr + (size_t)eb * 2048 + wgu * 8 + eu), pack,
                         __ATOMIC_RELAXED, __HIP_MEMORY_SCOPE_AGENT);
      if (!IS_L0)
        *(unsigned int*)(H1bf + ((size_t)eb * T + (t - 1)) * H + wgu * 8 + eu) = pack;
    }

    // publish: syncthreads (drain) + one flag store, zero contention
    publish_flag(IS_L0 ? (f0 + (size_t)t * 128 + wgu)
                       : (f1 + (size_t)(t - 1) * 128 + wgu));
  }
}

__global__ __launch_bounds__(256, 1)
void k_lstm_persistent(const u16* __restrict__ W0T, const u16* __restrict__ W1T,
                       const u16* __restrict__ xp0p, const float* __restrict__ b1,
                       u16* __restrict__ hseq, u16* __restrict__ H1bf,
                       int* __restrict__ sync) {
  __shared__ float red[4 * 2 * 2 * 16 * 16];   // 16KB
  int* f0 = sync;
  int* f1 = sync + 256 * 128;
  int wg = blockIdx.x;
  if (wg < 128)
    lstm_role<1024, true>(W0T, xp0p, nullptr, hseq, H1bf, f0, f1, red, wg);
  else
    lstm_role<2048, false>(W1T, nullptr, b1, hseq, H1bf, f0, f1, red, wg - 128);
}

// ---------------- softmax finalize ----------------
__global__ void k_rowfin(const float* __restrict__ pmax, const float* __restrict__ psum,
                         const float* __restrict__ Cl, const int* __restrict__ targets,
                         float* __restrict__ loss) {
  int row = blockIdx.x;
  int tid = threadIdx.x, lane = tid & 63, w = tid >> 6;
  float mx = -1e30f, s = 0.f;
  if (tid < NCH) { mx = pmax[(size_t)row * NCH + tid]; s = psum[(size_t)row * NCH + tid]; }
#pragma unroll
  for (int d = 1; d < 64; d <<= 1) {
    float mo = __shfl_xor(mx, d, 64);
    float so = __shfl_xor(s, d, 64);
    float M2 = fmaxf(mx, mo);
    s = s * __expf(mx - M2) + so * __expf(mo - M2);
    mx = M2;
  }
  __shared__ float2 wred[4];
  if (lane == 0) wred[w] = make_float2(mx, s);
  __syncthreads();
  if (tid == 0) {
    float M = wred[0].x, S = wred[0].y;
#pragma unroll
    for (int i = 1; i < 4; ++i) {
      float M2 = fmaxf(M, wred[i].x);
      S = S * __expf(M - M2) + wred[i].y * __expf(wred[i].x - M2);
      M = M2;
    }
    float logZ = M + logf(S);
    int tgt = targets[row];
    float xt = Cl[(size_t)row * V + tgt];
    loss[row] = logZ - xt;
  }
}

__global__ void k_cost(const float* __restrict__ loss, float* __restrict__ out) {
  int tid = threadIdx.x, lane = tid & 63, w = tid >> 6;
  float s = 0.f;
  for (int i = tid; i < BT; i += 256) s += loss[i];
#pragma unroll
  for (int d = 1; d < 64; d <<= 1) s += __shfl_xor(s, d, 64);
  __shared__ float ws4[4];
  if (lane == 0) ws4[w] = s;
  __syncthreads();
  if (tid == 0) out[0] = (ws4[0] + ws4[1] + ws4[2] + ws4[3]) * (1.0f / B);
}

// ---------------- host ----------------
extern "C" void kernel_launch(void* const* d_in, const int* in_sizes, int n_in,
                              void* d_out, int out_size, void* d_ws, size_t ws_size,
                              hipStream_t stream) {
  const int*   input_data = (const int*)d_in[0];
  const int*   targets    = (const int*)d_in[1];
  const float* emb        = (const float*)d_in[2];
  const float* softmax_b  = (const float*)d_in[3];
  const float* W0         = (const float*)d_in[4];
  const float* b0         = (const float*)d_in[5];
  const float* W1         = (const float*)d_in[6];
  const float* b1         = (const float*)d_in[7];
  float* out = (float*)d_out;
  char*  ws  = (char*)d_ws;

  u16*   W0T  = (u16*)(ws + OFF_W0T);
  u16*   W1T  = (u16*)(ws + OFF_W1T);
  u16*   Ebf  = (u16*)(ws + OFF_EBF);
  u16*   Xbf  = (u16*)(ws + OFF_XBF);
  u16*   xp0p = (u16*)(ws + OFF_XP0);
  u16*   H1bf = (u16*)(ws + OFF_H1);
  u16*   hseq = (u16*)(ws + OFF_HSEQ);
  int*   sync = (int*)(ws + OFF_SYNC);
  float* pmax = (float*)(ws + OFF_PMAX);
  float* psum = (float*)(ws + OFF_PSUM);
  float* lossb= (float*)(ws + OFF_LOSS);

  // prep: weight transposes (bf16), embedding convert, X gather, R[0..1]+flags zero
  k_transpose_cvt<<<dim3(G / 32, 2048 / 32), 256, 0, stream>>>(W0, W0T, 2048, G);
  k_transpose_cvt<<<dim3(G / 32, 2048 / 32), 256, 0, stream>>>(W1, W1T, 2048, G);
  k_cvt_bf16<<<2048, 256, 0, stream>>>(emb, Ebf, V * H / 4);
  k_gather_x<<<BT, 256, 0, stream>>>(emb, input_data, Xbf);
  k_zero<<<64, 256, 0, stream>>>((unsigned int*)(ws + OFF_HSEQ), RSTRIDE);  // R[0],R[1]
  k_zero<<<64, 256, 0, stream>>>((unsigned int*)(ws + OFF_SYNC), (int)(SZ_SYNC / 4));

  // xp0p = X @ W0[0:1024,:] + b0  (bf16, block-permuted layout)
  k_gemm<false, 1><<<dim3(G / 128, BT / 128), 256, 0, stream>>>(
      Xbf, H, W0T, 2048, (float*)xp0p, G, b0, H, nullptr, nullptr, 0);

  // persistent pipelined LSTM: flag-sync decoupled chains, weights in VGPRs
  k_lstm_persistent<<<dim3(NWG2), dim3(256), 0, stream>>>(
      W0T, W1T, xp0p, b1, hseq, H1bf, sync);

  // logits = H1 @ E^T + softmax_b, fused online-softmax partials
  k_gemm<true, 0><<<dim3(V / 128, BT / 128), 256, 0, stream>>>(
      H1bf, H, Ebf, H, out, V, softmax_b, H, pmax, psum, NCH);

  // per-row logZ + NLL, then cost = sum/B appended after logits
  k_rowfin<<<BT, 256, 0, stream>>>(pmax, psum, out, targets, lossb);
  k_cost<<<1, 256, 0, stream>>>(lossb, out + (size_t)BT * V);
}

// Round 8
// 2990.636 us; speedup vs baseline: 1.0668x; 1.0021x over previous
//
#include <hip/hip_runtime.h>
#include <hip/hip_bf16.h>

#define DEV static __device__ __forceinline__

typedef unsigned short u16;
typedef unsigned long long u64;
typedef __attribute__((ext_vector_type(8))) short short8;   // 8 bf16 (4 VGPRs) MFMA frag
typedef __attribute__((ext_vector_type(4))) float f32x4;    // MFMA accumulator

constexpr int V = 32000, H = 1024, B = 32, T = 256;
constexpr int BT = B * T;       // 8192 rows
constexpr int G  = 4 * H;       // 4096 gates
constexpr int NCH = V / 256;    // 125 col-chunks for softmax partials (256-wide tiles)
constexpr int NWG2 = 256;       // persistent LSTM blocks (128 L0 + 128 L1), 1/CU
constexpr int RSTRIDE = 32 * 2048 + 2048;  // u16 per h-buffer (132KB incl 4KB pad)

// ---------------- workspace layout (bytes) ----------------
constexpr size_t SZ_WT    = (size_t)G * 2048 * 2;            // [4096][2048] bf16
constexpr size_t OFF_W0T  = 0;
constexpr size_t OFF_W1T  = OFF_W0T + SZ_WT;
constexpr size_t OFF_EBF  = OFF_W1T + SZ_WT;                 // [32000][1024] bf16
constexpr size_t OFF_XBF  = OFF_EBF + (size_t)V * H * 2;     // [8192][1024] bf16 (row = t*32+b)
constexpr size_t OFF_XP0  = OFF_XBF + (size_t)BT * H * 2;    // bf16 perm [t][wgu][b][q*8+uu]
constexpr size_t OFF_H1   = OFF_XP0 + (size_t)BT * G * 2;    // [8192][1024] bf16 (row = b*256+t)
constexpr size_t OFF_HSEQ = OFF_H1 + (size_t)BT * H * 2;     // R[0..T+1], write-once per tick
constexpr size_t SZ_HSEQ  = (size_t)(T + 2) * RSTRIDE * 2;
constexpr size_t OFF_SYNC = OFF_HSEQ + SZ_HSEQ;              // flags f0/f1 [256][128] ints
constexpr size_t SZ_SYNC  = (size_t)2 * 256 * 128 * 4;       // 256KB
constexpr size_t OFF_PMAX = OFF_SYNC + SZ_SYNC;              // [8192][125] f32
constexpr size_t OFF_PSUM = OFF_PMAX + (size_t)BT * NCH * 4;
constexpr size_t OFF_LOSS = OFF_PSUM + (size_t)BT * NCH * 4; // [8192] f32

DEV u16 f2bf(float x) {  // RNE f32 -> bf16 bits
  union { float f; unsigned int u; } v; v.f = x;
  unsigned int r = v.u + 0x7fffu + ((v.u >> 16) & 1u);
  return (u16)(r >> 16);
}
DEV float bf2f(u16 b) {
  union { unsigned int u; float f; } v; v.u = ((unsigned int)b) << 16;
  return v.f;
}
DEV float sigm(float x) { return 1.f / (1.f + expf(-x)); }

DEV void gload_lds16(const u16* g, u16* l) {
  __builtin_amdgcn_global_load_lds(
      (__attribute__((address_space(1))) void*)g,
      (__attribute__((address_space(3))) void*)l, 16, 0, 0);
}

// ---------------- prep kernels ----------------

__global__ void k_transpose_cvt(const float* __restrict__ in, u16* __restrict__ out,
                                int R, int C) {
  __shared__ float tile[32][33];
  int bc = blockIdx.x * 32, br = blockIdx.y * 32;
  int tx = threadIdx.x & 31, ty0 = threadIdx.x >> 5;
#pragma unroll
  for (int i = 0; i < 4; ++i) {
    int ty = ty0 + i * 8;
    tile[ty][tx] = in[(size_t)(br + ty) * C + bc + tx];
  }
  __syncthreads();
#pragma unroll
  for (int i = 0; i < 4; ++i) {
    int ty = ty0 + i * 8;
    out[(size_t)(bc + ty) * R + br + tx] = f2bf(tile[tx][ty]);
  }
}

__global__ void k_cvt_bf16(const float* __restrict__ in, u16* __restrict__ out, int n4) {
  int i = blockIdx.x * blockDim.x + threadIdx.x;
  int stride = gridDim.x * blockDim.x;
  for (; i < n4; i += stride) {
    float4 v = ((const float4*)in)[i];
    ushort4 o;
    o.x = f2bf(v.x); o.y = f2bf(v.y); o.z = f2bf(v.z); o.w = f2bf(v.w);
    ((ushort4*)out)[i] = o;
  }
}

__global__ void k_gather_x(const float* __restrict__ emb, const int* __restrict__ inp,
                           u16* __restrict__ Xbf) {
  int row = blockIdx.x;
  int t = row >> 5, b = row & 31;
  int tok = inp[b * T + t];
  const float4* src = (const float4*)(emb + (size_t)tok * H);
  ushort4* dst = (ushort4*)(Xbf + (size_t)row * H);
  float4 v = src[threadIdx.x];
  ushort4 o;
  o.x = f2bf(v.x); o.y = f2bf(v.y); o.z = f2bf(v.z); o.w = f2bf(v.w);
  dst[threadIdx.x] = o;
}

__global__ void k_zero(unsigned int* __restrict__ p, int nwords) {
  int i = blockIdx.x * blockDim.x + threadIdx.x;
  int stride = gridDim.x * blockDim.x;
  for (; i < nwords; i += stride) p[i] = 0u;
}

// ---------------- 128x128 bf16 MFMA GEMM (m97 structure, for xp0) --------
// CMODE 1: C bf16, permuted [t][wgu][b][q*8+uu] (xp0 layout for LSTM).
template <int CMODE>
__global__ __launch_bounds__(256)
void k_gemm(const u16* __restrict__ A, int lda,
            const u16* __restrict__ Bt, int ldb,
            float* __restrict__ C, int ldc,
            const float* __restrict__ bias, int K) {
  __shared__ alignas(16) u16 ldsA[128 * 32];
  __shared__ alignas(16) u16 ldsB[128 * 32];

  unsigned nwg = gridDim.x * gridDim.y;
  unsigned flat = blockIdx.y * gridDim.x + blockIdx.x;
  unsigned nf = (flat & 7) * (nwg >> 3) + (flat >> 3);
  unsigned bx = nf % gridDim.x, by = nf / gridDim.x;

  int tid = threadIdx.x, lane = tid & 63, w = tid >> 6;
  int row0 = by * 128, col0 = bx * 128;
  int wr = w >> 1, wc = w & 1;
  int c15 = lane & 15, q4 = lane >> 4;

  const u16* ag[2]; const u16* bg[2];
#pragma unroll
  for (int j = 0; j < 2; ++j) {
    int r = (j * 4 + w) * 16 + (lane >> 2);
    int k = (lane & 3) * 8;
    ag[j] = A + (size_t)(row0 + r) * lda + k;
    bg[j] = Bt + (size_t)(col0 + r) * ldb + k;
  }
  u16* lA0 = ldsA + (size_t)(0 + w) * 512;
  u16* lA1 = ldsA + (size_t)(4 + w) * 512;
  u16* lB0 = ldsB + (size_t)(0 + w) * 512;
  u16* lB1 = ldsB + (size_t)(4 + w) * 512;

  f32x4 acc[4][4];
#pragma unroll
  for (int m = 0; m < 4; ++m)
#pragma unroll
    for (int n = 0; n < 4; ++n) acc[m][n] = (f32x4){0.f, 0.f, 0.f, 0.f};

  int nk = K >> 5;
  for (int kk = 0; kk < nk; ++kk) {
    int kb = kk * 32;
    gload_lds16(ag[0] + kb, lA0);
    gload_lds16(ag[1] + kb, lA1);
    gload_lds16(bg[0] + kb, lB0);
    gload_lds16(bg[1] + kb, lB1);
    __syncthreads();

    short8 af[4], bfr[4];
#pragma unroll
    for (int m = 0; m < 4; ++m)
      af[m] = *(const short8*)(ldsA + (wr * 64 + m * 16 + c15) * 32 + q4 * 8);
#pragma unroll
    for (int n = 0; n < 4; ++n)
      bfr[n] = *(const short8*)(ldsB + (wc * 64 + n * 16 + c15) * 32 + q4 * 8);
#pragma unroll
    for (int m = 0; m < 4; ++m)
#pragma unroll
      for (int n = 0; n < 4; ++n)
        acc[m][n] = __builtin_amdgcn_mfma_f32_16x16x32_bf16(af[m], bfr[n], acc[m][n], 0, 0, 0);
    __syncthreads();
  }

  float bias_n[4];
#pragma unroll
  for (int n = 0; n < 4; ++n) bias_n[n] = bias[col0 + wc * 64 + n * 16 + c15];

#pragma unroll
  for (int m = 0; m < 4; ++m) {
#pragma unroll
    for (int jr = 0; jr < 4; ++jr) {
      int r_g = row0 + wr * 64 + m * 16 + q4 * 4 + jr;
#pragma unroll
      for (int n = 0; n < 4; ++n) {
        int c_g = col0 + wc * 64 + n * 16 + c15;
        float val = acc[m][n][jr] + bias_n[n];
        if (CMODE == 0) {
          C[(size_t)r_g * ldc + c_g] = val;
        } else {
          int tt = r_g >> 5, bb = r_g & 31;
          int q = c_g >> 10, wgup = (c_g & 1023) >> 3, uu = c_g & 7;
          ((u16*)C)[((((size_t)tt * 128 + wgup) * 32 + bb) * 32) + q * 8 + uu] = f2bf(val);
        }
      }
    }
  }
}

// ---------------- 256x256 8-wave counted-vmcnt GEMM (logits) --------------
// BK=32, 64KB LDS double-buffer, half-tile ring staged by global_load_lds,
// vmcnt(3) maintained (never drained mid-loop), 2 phases/K-tile with
// {ds_read || stage -> barrier -> lgkmcnt(0) -> setprio(1) 16xMFMA}, XOR
// unit-swizzle applied on BOTH stage-source and frag-read (rule #21).
// K fixed = 1024 (32 tiles). Grid (125, 32), 512 threads.
constexpr int GNT = 32;  // K-tiles

DEV void stage_half256(const u16* __restrict__ A, int lda,
                       const u16* __restrict__ Bt, int ldb,
                       int row0, int col0, u16* lds, int Hh, int tid) {
  int t = Hh >> 2, j = Hh & 3, op = j >> 1, hh = j & 1;
  int wid = tid >> 6, lane = tid & 63;
  int r = hh * 128 + wid * 16 + (lane >> 2);
  // XOR unit-swizzle: unit (lane&3) ^ (row&3)  [involution, both sides]
  int k = t * 32 + (((lane & 3) ^ ((lane >> 2) & 3)) << 3);
  const u16* g = (op == 0) ? (A + (size_t)(row0 + r) * lda + k)
                           : (Bt + (size_t)(col0 + r) * ldb + k);
  u16* l = lds + (size_t)((op * 2 + (t & 1)) * 8192 + (hh * 128 + wid * 16) * 32);
  gload_lds16(g, l);
}

template <bool SM_EPI>
__global__ __launch_bounds__(512)
void k_gemm256(const u16* __restrict__ A, int lda,
               const u16* __restrict__ Bt, int ldb,
               float* __restrict__ C, int ldc,
               const float* __restrict__ bias,
               float* __restrict__ pmax, float* __restrict__ psum, int nch) {
  __shared__ alignas(16) u16 lds[4 * 8192];   // 64KB: [op][pt][256*32]

  unsigned nwg = gridDim.x * gridDim.y;       // 4000, %8==0
  unsigned flat = blockIdx.y * gridDim.x + blockIdx.x;
  unsigned nf = (flat & 7) * (nwg >> 3) + (flat >> 3);
  int bx = nf % gridDim.x, by = nf / gridDim.x;
  int row0 = by * 256, col0 = bx * 256;

  int tid = threadIdx.x, lane = tid & 63, wid = tid >> 6;
  int wr = wid >> 2, wc = wid & 3;            // 2M x 4N waves
  int c15 = lane & 15, q4 = lane >> 4;
  int usw = (q4 ^ (c15 & 3)) << 3;            // swizzled unit offset (elements)

  f32x4 acc[8][4];
#pragma unroll
  for (int m = 0; m < 8; ++m)
#pragma unroll
    for (int n = 0; n < 4; ++n) acc[m][n] = (f32x4){0.f, 0.f, 0.f, 0.f};

  // prologue: stage halves 0..6 (tile0 complete + 3 of tile1)
#pragma unroll
  for (int h = 0; h < 7; ++h)
    stage_half256(A, lda, Bt, ldb, row0, col0, lds, h, tid);
  asm volatile("s_waitcnt vmcnt(3)" ::: "memory");
  __builtin_amdgcn_sched_barrier(0);
  __builtin_amdgcn_s_barrier();

  int Hh = 7;
  short8 af[4], bfr[4];

  for (int t = 0; t < GNT; ++t) {
    int pt = t & 1;
    const u16* la = lds + pt * 8192;
    const u16* lb = lds + (2 + pt) * 8192;

    // ---- phase 0: m 0..3 ----
#pragma unroll
    for (int m = 0; m < 4; ++m)
      af[m] = *(const short8*)(la + (wr * 128 + m * 16 + c15) * 32 + usw);
#pragma unroll
    for (int n = 0; n < 4; ++n)
      bfr[n] = *(const short8*)(lb + (wc * 64 + n * 16 + c15) * 32 + usw);
    if (Hh < 4 * GNT) { stage_half256(A, lda, Bt, ldb, row0, col0, lds, Hh, tid); ++Hh; }
    if (Hh < 4 * GNT) { stage_half256(A, lda, Bt, ldb, row0, col0, lds, Hh, tid); ++Hh; }
    __builtin_amdgcn_s_barrier();
    asm volatile("s_waitcnt lgkmcnt(0)" ::: "memory");
    __builtin_amdgcn_sched_barrier(0);
    __builtin_amdgcn_s_setprio(1);
#pragma unroll
    for (int m = 0; m < 4; ++m)
#pragma unroll
      for (int n = 0; n < 4; ++n)
        acc[m][n] = __builtin_amdgcn_mfma_f32_16x16x32_bf16(af[m], bfr[n], acc[m][n], 0, 0, 0);
    __builtin_amdgcn_s_setprio(0);
    __builtin_amdgcn_s_barrier();

    // ---- phase 1: m 4..7 ----
#pragma unroll
    for (int m = 0; m < 4; ++m)
      af[m] = *(const short8*)(la + (wr * 128 + (m + 4) * 16 + c15) * 32 + usw);
    if (Hh < 4 * GNT) { stage_half256(A, lda, Bt, ldb, row0, col0, lds, Hh, tid); ++Hh; }
    if (Hh < 4 * GNT) { stage_half256(A, lda, Bt, ldb, row0, col0, lds, Hh, tid); ++Hh; }
    __builtin_amdgcn_s_barrier();
    asm volatile("s_waitcnt lgkmcnt(0)" ::: "memory");
    __builtin_amdgcn_sched_barrier(0);
    __builtin_amdgcn_s_setprio(1);
#pragma unroll
    for (int m = 0; m < 4; ++m)
#pragma unroll
      for (int n = 0; n < 4; ++n)
        acc[m + 4][n] = __builtin_amdgcn_mfma_f32_16x16x32_bf16(af[m], bfr[n], acc[m + 4][n], 0, 0, 0);
    __builtin_amdgcn_s_setprio(0);
    // counted vmcnt once per K-tile (never 0 until the tail)
    if (t < GNT - 2) {
      asm volatile("s_waitcnt vmcnt(3)" ::: "memory");
      __builtin_amdgcn_sched_barrier(0);
    } else if (t == GNT - 2) {
      asm volatile("s_waitcnt vmcnt(0)" ::: "memory");
      __builtin_amdgcn_sched_barrier(0);
    }
    __builtin_amdgcn_s_barrier();
  }

  // ---- epilogue: bias + C write + online-softmax partials ----
  float bias_n[4];
#pragma unroll
  for (int n = 0; n < 4; ++n) bias_n[n] = bias[col0 + wc * 64 + n * 16 + c15];

  float2* red = (float2*)lds;   // overlay [256][4]
  __syncthreads();

#pragma unroll
  for (int m = 0; m < 8; ++m) {
#pragma unroll
    for (int jr = 0; jr < 4; ++jr) {
      int rloc = wr * 128 + m * 16 + q4 * 4 + jr;
      int r_g = row0 + rloc;
      float v[4];
#pragma unroll
      for (int n = 0; n < 4; ++n) {
        int c_g = col0 + wc * 64 + n * 16 + c15;
        float val = acc[m][n][jr] + bias_n[n];
        C[(size_t)r_g * ldc + c_g] = val;
        v[n] = val;
      }
      if (SM_EPI) {
        float mx = fmaxf(fmaxf(v[0], v[1]), fmaxf(v[2], v[3]));
        float s = __expf(v[0] - mx) + __expf(v[1] - mx) + __expf(v[2] - mx) + __expf(v[3] - mx);
#pragma unroll
        for (int d = 1; d < 16; d <<= 1) {
          float mo = __shfl_xor(mx, d, 64);
          float so = __shfl_xor(s, d, 64);
          float M2 = fmaxf(mx, mo);
          s = s * __expf(mx - M2) + so * __expf(mo - M2);
          mx = M2;
        }
        if (c15 == 0) red[rloc * 4 + wc] = make_float2(mx, s);
      }
    }
  }
  if (SM_EPI) {
    __syncthreads();
    if (tid < 256) {
      float M = -1e30f, S = 0.f;
#pragma unroll
      for (int i = 0; i < 4; ++i) {
        float2 a = red[tid * 4 + i];
        float M2 = fmaxf(M, a.x);
        S = S * __expf(M - M2) + a.y * __expf(a.x - M2);
        M = M2;
      }
      pmax[(size_t)(row0 + tid) * nch + bx] = M;
      psum[(size_t)(row0 + tid) * nch + bx] = S;
    }
  }
}

// ---------------- persistent LSTM: weights in VGPRs, flag-sync chains -----

#define RED(w_, bt_, nt_, r_, c_) red[((((w_)*2 + (bt_)) * 2 + (nt_)) * 16 + (r_)) * 16 + (c_)]

DEV void wait_flags(const int* __restrict__ fa, const int* __restrict__ fb) {
  if (threadIdx.x < 64) {
    int lane = threadIdx.x;
    while (true) {
      int ok = 1;
      if (fa) {
        int a0 = __hip_atomic_load(fa + lane,      __ATOMIC_RELAXED, __HIP_MEMORY_SCOPE_AGENT);
        int a1 = __hip_atomic_load(fa + 64 + lane, __ATOMIC_RELAXED, __HIP_MEMORY_SCOPE_AGENT);
        ok &= (a0 != 0) & (a1 != 0);
      }
      if (fb) {
        int b0 = __hip_atomic_load(fb + lane,      __ATOMIC_RELAXED, __HIP_MEMORY_SCOPE_AGENT);
        int b1 = __hip_atomic_load(fb + 64 + lane, __ATOMIC_RELAXED, __HIP_MEMORY_SCOPE_AGENT);
        ok &= (b0 != 0) & (b1 != 0);
      }
      if (__all(ok)) break;
      __builtin_amdgcn_s_sleep(1);
    }
  }
  __builtin_amdgcn_sched_barrier(0);
  __syncthreads();
}

DEV void publish_flag(int* __restrict__ word) {
  __syncthreads();   // each wave's vmcnt drained -> agent h-stores at L3
  if (threadIdx.x == 0)
    __hip_atomic_store(word, 1, __ATOMIC_RELAXED, __HIP_MEMORY_SCOPE_AGENT);
}

template <int KH, bool IS_L0>
DEV void lstm_role(const u16* __restrict__ WT,      // [4096][2048] bf16
                   const u16* __restrict__ xp0p,    // bf16 perm (L0) or null
                   const float* __restrict__ zb1,   // b1 (L1) or null
                   u16* __restrict__ hseq, u16* __restrict__ H1bf,
                   int* __restrict__ f0, int* __restrict__ f1,
                   float* __restrict__ red, int wgu) {
  constexpr int KOFF = IS_L0 ? 1024 : 0;   // weight-k offset (h-part of W0)
  constexpr int KS = KH / 4;               // per-wave K slice
  constexpr int NKC = KS / 32;             // k-chunks per wave (8 or 16)
  int tid = threadIdx.x, lane = tid & 63, w = tid >> 6;
  int c15 = lane & 15, q4 = lane >> 4;
  int eb = tid >> 3, eu = tid & 7;         // epilogue identity: (b, unit)

  // ---- preload weight slice into registers (once) ----
  short8 wfr[2][NKC];
#pragma unroll
  for (int nt = 0; nt < 2; ++nt) {
    int lr = nt * 16 + c15;                // local row = gate*8 + unit
    const u16* rp = WT + (size_t)((lr >> 3) * 1024 + wgu * 8 + (lr & 7)) * 2048
                    + KOFF + w * KS + q4 * 8;
#pragma unroll
    for (int kc = 0; kc < NKC; ++kc)
      wfr[nt][kc] = *(const short8*)(rp + kc * 32);
  }

  float zpc[4];
  if (!IS_L0) {
#pragma unroll
    for (int q = 0; q < 4; ++q) zpc[q] = zb1[q * 1024 + wgu * 8 + eu];
  }
  float creg = 0.f;                        // c-state lives in a register

  for (int it_t = 0; it_t < T; ++it_t) {
    int t = IS_L0 ? it_t : it_t + 1;       // L0 computes h0(t); L1 computes h1(t-1)

    float zp[4];
    if (IS_L0) {
      // tick-private data: issue BEFORE the flag wait to hide latency
#pragma unroll
      for (int q = 0; q < 4; ++q)
        zp[q] = bf2f(xp0p[((((size_t)t * 128 + wgu) * 32 + eb) * 32) + q * 8 + eu]);
    } else {
#pragma unroll
      for (int q = 0; q < 4; ++q) zp[q] = zpc[q];
    }

    if (IS_L0) {
      if (t >= 1) wait_flags(f0 + (size_t)(t - 1) * 128, nullptr);  // h0(t-1)
    } else {
      wait_flags(f0 + (size_t)(t - 1) * 128,                        // h0(t-1)
                 t >= 2 ? f1 + (size_t)(t - 2) * 128 : nullptr);    // h1(t-2)
    }

    const u16* hread = hseq + (size_t)t * RSTRIDE;
    f32x4 acc[2][2];
#pragma unroll
    for (int bt = 0; bt < 2; ++bt)
#pragma unroll
      for (int nt = 0; nt < 2; ++nt) acc[bt][nt] = (f32x4){0.f, 0.f, 0.f, 0.f};

#pragma unroll
    for (int kc = 0; kc < NKC; ++kc) {
      int kh = w * KS + kc * 32 + q4 * 8;
      short8 a0 = *(const short8*)(hread + (size_t)c15 * 2048 + kh);
      short8 a1 = *(const short8*)(hread + (size_t)(16 + c15) * 2048 + kh);
      acc[0][0] = __builtin_amdgcn_mfma_f32_16x16x32_bf16(a0, wfr[0][kc], acc[0][0], 0, 0, 0);
      acc[0][1] = __builtin_amdgcn_mfma_f32_16x16x32_bf16(a0, wfr[1][kc], acc[0][1], 0, 0, 0);
      acc[1][0] = __builtin_amdgcn_mfma_f32_16x16x32_bf16(a1, wfr[0][kc], acc[1][0], 0, 0, 0);
      acc[1][1] = __builtin_amdgcn_mfma_f32_16x16x32_bf16(a1, wfr[1][kc], acc[1][1], 0, 0, 0);
    }

    // cross-wave K reduction via LDS
#pragma unroll
    for (int bt = 0; bt < 2; ++bt)
#pragma unroll
      for (int nt = 0; nt < 2; ++nt)
#pragma unroll
        for (int jr = 0; jr < 4; ++jr)
          RED(w, bt, nt, q4 * 4 + jr, c15) = acc[bt][nt][jr];
    __syncthreads();

    // epilogue: thread = (b=eb, unit=eu)
    int bt = eb >> 4, rr = eb & 15;
    float z[4];
#pragma unroll
    for (int q = 0; q < 4; ++q) {
      int lr = q * 8 + eu, nt = lr >> 4, cc = lr & 15;
      z[q] = RED(0, bt, nt, rr, cc) + RED(1, bt, nt, rr, cc) +
             RED(2, bt, nt, rr, cc) + RED(3, bt, nt, rr, cc) + zp[q];
    }
    float gi = sigm(z[0]);
    float gj = tanhf(z[1]);
    float gf = sigm(z[2] + 1.f);   // forget_bias = 1.0
    float go = sigm(z[3]);
    creg = creg * gf + gi * gj;
    float hv = go * tanhf(creg);

    int hb = (int)f2bf(hv);
    int hp = __shfl_xor(hb, 1, 64);  // partner unit (eu^1), same b
    if (!(tid & 1)) {
      unsigned int pack = (unsigned int)(u16)hb | ((unsigned int)(u16)hp << 16);
      u16* hwr = hseq + (size_t)(t + 1) * RSTRIDE + (IS_L0 ? 0 : 1024);
      __hip_atomic_store((unsigned int*)(hwr + (size_t)eb * 2048 + wgu * 8 + eu), pack,
                         __ATOMIC_RELAXED, __HIP_MEMORY_SCOPE_AGENT);
      if (!IS_L0)
        __builtin_nontemporal_store(pack,
            (unsigned int*)(H1bf + ((size_t)eb * T + (t - 1)) * H + wgu * 8 + eu));
    }

    // publish: syncthreads (drain) + one flag store, zero contention
    publish_flag(IS_L0 ? (f0 + (size_t)t * 128 + wgu)
                       : (f1 + (size_t)(t - 1) * 128 + wgu));
  }
}

__global__ __launch_bounds__(256, 1)
void k_lstm_persistent(const u16* __restrict__ W0T, const u16* __restrict__ W1T,
                       const u16* __restrict__ xp0p, const float* __restrict__ b1,
                       u16* __restrict__ hseq, u16* __restrict__ H1bf,
                       int* __restrict__ sync) {
  __shared__ float red[4 * 2 * 2 * 16 * 16];   // 16KB
  int* f0 = sync;
  int* f1 = sync + 256 * 128;
  int wg = blockIdx.x;
  if (wg < 128)
    lstm_role<1024, true>(W0T, xp0p, nullptr, hseq, H1bf, f0, f1, red, wg);
  else
    lstm_role<2048, false>(W1T, nullptr, b1, hseq, H1bf, f0, f1, red, wg - 128);
}

// ---------------- softmax finalize ----------------
__global__ void k_rowfin(const float* __restrict__ pmax, const float* __restrict__ psum,
                         const float* __restrict__ Cl, const int* __restrict__ targets,
                         float* __restrict__ loss) {
  int row = blockIdx.x;
  int tid = threadIdx.x, lane = tid & 63, w = tid >> 6;
  float mx = -1e30f, s = 0.f;
  if (tid < NCH) { mx = pmax[(size_t)row * NCH + tid]; s = psum[(size_t)row * NCH + tid]; }
#pragma unroll
  for (int d = 1; d < 64; d <<= 1) {
    float mo = __shfl_xor(mx, d, 64);
    float so = __shfl_xor(s, d, 64);
    float M2 = fmaxf(mx, mo);
    s = s * __expf(mx - M2) + so * __expf(mo - M2);
    mx = M2;
  }
  __shared__ float2 wred[4];
  if (lane == 0) wred[w] = make_float2(mx, s);
  __syncthreads();
  if (tid == 0) {
    float M = wred[0].x, S = wred[0].y;
#pragma unroll
    for (int i = 1; i < 4; ++i) {
      float M2 = fmaxf(M, wred[i].x);
      S = S * __expf(M - M2) + wred[i].y * __expf(wred[i].x - M2);
      M = M2;
    }
    float logZ = M + logf(S);
    int tgt = targets[row];
    float xt = Cl[(size_t)row * V + tgt];
    loss[row] = logZ - xt;
  }
}

__global__ void k_cost(const float* __restrict__ loss, float* __restrict__ out) {
  int tid = threadIdx.x, lane = tid & 63, w = tid >> 6;
  float s = 0.f;
  for (int i = tid; i < BT; i += 256) s += loss[i];
#pragma unroll
  for (int d = 1; d < 64; d <<= 1) s += __shfl_xor(s, d, 64);
  __shared__ float ws4[4];
  if (lane == 0) ws4[w] = s;
  __syncthreads();
  if (tid == 0) out[0] = (ws4[0] + ws4[1] + ws4[2] + ws4[3]) * (1.0f / B);
}

// ---------------- host ----------------
extern "C" void kernel_launch(void* const* d_in, const int* in_sizes, int n_in,
                              void* d_out, int out_size, void* d_ws, size_t ws_size,
                              hipStream_t stream) {
  const int*   input_data = (const int*)d_in[0];
  const int*   targets    = (const int*)d_in[1];
  const float* emb        = (const float*)d_in[2];
  const float* softmax_b  = (const float*)d_in[3];
  const float* W0         = (const float*)d_in[4];
  const float* b0         = (const float*)d_in[5];
  const float* W1         = (const float*)d_in[6];
  const float* b1         = (const float*)d_in[7];
  float* out = (float*)d_out;
  char*  ws  = (char*)d_ws;

  u16*   W0T  = (u16*)(ws + OFF_W0T);
  u16*   W1T  = (u16*)(ws + OFF_W1T);
  u16*   Ebf  = (u16*)(ws + OFF_EBF);
  u16*   Xbf  = (u16*)(ws + OFF_XBF);
  u16*   xp0p = (u16*)(ws + OFF_XP0);
  u16*   H1bf = (u16*)(ws + OFF_H1);
  u16*   hseq = (u16*)(ws + OFF_HSEQ);
  int*   sync = (int*)(ws + OFF_SYNC);
  float* pmax = (float*)(ws + OFF_PMAX);
  float* psum = (float*)(ws + OFF_PSUM);
  float* lossb= (float*)(ws + OFF_LOSS);

  // prep: weight transposes (bf16), embedding convert, X gather, R[0..1]+flags zero
  k_transpose_cvt<<<dim3(G / 32, 2048 / 32), 256, 0, stream>>>(W0, W0T, 2048, G);
  k_transpose_cvt<<<dim3(G / 32, 2048 / 32), 256, 0, stream>>>(W1, W1T, 2048, G);
  k_cvt_bf16<<<2048, 256, 0, stream>>>(emb, Ebf, V * H / 4);
  k_gather_x<<<BT, 256, 0, stream>>>(emb, input_data, Xbf);
  k_zero<<<64, 256, 0, stream>>>((unsigned int*)(ws + OFF_HSEQ), RSTRIDE);  // R[0],R[1]
  k_zero<<<64, 256, 0, stream>>>((unsigned int*)(ws + OFF_SYNC), (int)(SZ_SYNC / 4));

  // xp0p = X @ W0[0:1024,:] + b0  (bf16, block-permuted layout)
  k_gemm<1><<<dim3(G / 128, BT / 128), 256, 0, stream>>>(
      Xbf, H, W0T, 2048, (float*)xp0p, G, b0, H);

  // persistent pipelined LSTM: flag-sync decoupled chains, weights in VGPRs
  k_lstm_persistent<<<dim3(NWG2), dim3(256), 0, stream>>>(
      W0T, W1T, xp0p, b1, hseq, H1bf, sync);

  // logits = H1 @ E^T + softmax_b, 256^2 counted-vmcnt GEMM + softmax partials
  k_gemm256<true><<<dim3(V / 256, BT / 256), 512, 0, stream>>>(
      H1bf, H, Ebf, H, out, V, softmax_b, pmax, psum, NCH);

  // per-row logZ + NLL, then cost = sum/B appended after logits
  k_rowfin<<<BT, 256, 0, stream>>>(pmax, psum, out, targets, lossb);
  k_cost<<<1, 256, 0, stream>>>(lossb, out + (size_t)BT * V);
}